// Round 9
// baseline (193.728 us; speedup 1.0000x reference)
//
#include <hip/hip_runtime.h>

#define DI __device__ __forceinline__

typedef __bf16 bf16;
typedef __bf16 bf16x8 __attribute__((ext_vector_type(8)));
typedef __bf16 bf16x4 __attribute__((ext_vector_type(4)));
typedef float  f32x4  __attribute__((ext_vector_type(4)));

DI void async_copy16(const void* g, void* s) {
  __builtin_amdgcn_global_load_lds(
      (__attribute__((address_space(1))) unsigned int*)(void*)g,
      (__attribute__((address_space(3))) unsigned int*)s,
      16, 0, 0);
}

DI f32x4 mfma16(bf16x8 a, bf16x8 b, f32x4 c) {
  return __builtin_amdgcn_mfma_f32_16x16x32_bf16(a, b, c, 0, 0, 0);
}

// ---------------------------------------------------------------- prep kernel
// z==4: x fp32 -> bf16 (1024 virtual blocks x 4096 elems).
// z<4 : Wt[z*1024 + n][k] = W_z[k][n] (bf16) — B^T layout for gemm_bt.
__global__ __launch_bounds__(256) void prep(const float* __restrict__ x,
                                            const float* __restrict__ Wq,
                                            const float* __restrict__ Wk,
                                            const float* __restrict__ Wv,
                                            const float* __restrict__ Wp,
                                            bf16* __restrict__ xb,
                                            bf16* __restrict__ Wt) {
  if (blockIdx.z == 4) {
    int blk = blockIdx.y * 32 + blockIdx.x;  // 0..1023
    int base = blk * 4096 + threadIdx.x * 4;
#pragma unroll
    for (int j = 0; j < 4; ++j) {
      float4 v = *(const float4*)&x[base + j * 1024];
      bf16x4 o;
      o[0] = (bf16)v.x; o[1] = (bf16)v.y; o[2] = (bf16)v.z; o[3] = (bf16)v.w;
      *(bf16x4*)&xb[base + j * 1024] = o;
    }
    return;
  }
  __shared__ float tile[32][33];
  const float* W = (blockIdx.z == 0) ? Wq : (blockIdx.z == 1) ? Wk
                 : (blockIdx.z == 2) ? Wv : Wp;
  int n0 = blockIdx.x * 32, k0 = blockIdx.y * 32;
  int tx = threadIdx.x & 31, ty = threadIdx.x >> 5;  // virtual (32,8)
#pragma unroll
  for (int i = 0; i < 4; ++i)
    tile[ty + i * 8][tx] = W[(k0 + ty + i * 8) * 1024 + n0 + tx];
  __syncthreads();
#pragma unroll
  for (int i = 0; i < 4; ++i)
    Wt[((int)blockIdx.z * 1024 + n0 + ty + i * 8) * 1024 + k0 + tx] =
        (bf16)tile[tx][ty + i * 8];
}

// ---------------------------------------------------------------- GEMM (B^T)
// C[m][n] = sum_k A[m][k] * Bt[n][k]  + bias.   BK=64 (rows = 128 B = 32 banks)
// with XOR-8 chunk swizzle on LDS tiles (2-way bank aliasing only, free).
// NW4 = waves/block. NW4==2: 128 threads, wave tile 64xNT (wave w owns rows
//   w*64..+64, ALL NT cols) -> 64 FLOP per LDS byte (2x the 4-wave 64x64
//   arrangement; LDS-read-bound ceiling rises ~30%->~45% MfmaUtil).
// NW4==4: 256 threads, 2x2 wave grid, wave tile (MT/2)x(NT/2).
// MODE 0: N=3072 QKV. Writes Q (pre-scaled (1/8)log2e), K as [B,H,S,64] bf16;
//   V as [B,H,64,S] bf16.
// MODE 1: N=1024 proj -> fp32 [4096][1024] + bias.
template <int MODE, int MT, int NT, int NW4>
__global__ __launch_bounds__(NW4 * 64, NW4 == 2 ? 2 : 3) void gemm_bt(
    const bf16* __restrict__ A, const bf16* __restrict__ Bt,
    const float* __restrict__ bias0, const float* __restrict__ bias1,
    const float* __restrict__ bias2, bf16* __restrict__ Qo,
    bf16* __restrict__ Ko, bf16* __restrict__ Vo, float* __restrict__ Po) {
  constexpr int NTH = NW4 * 64;
  constexpr int MW = MT / 2;
  constexpr int NWc = (NW4 == 4) ? NT / 2 : NT;  // cols per wave
  constexpr int MI = MW / 16, NI = NWc / 16;
  const int tid = threadIdx.x;
  const int w = tid >> 6, lane = tid & 63, quad = lane >> 4, m16 = lane & 15;
  const int m0 = blockIdx.x * MT, n0 = blockIdx.y * NT;
  const int mw = (NW4 == 4 ? (w >> 1) : w) * MW;
  const int nw = (NW4 == 4 ? (w & 1) : 0) * (NT / 2);
  const int sw = m16 & 7;

  __shared__ __align__(16) bf16 As[MT * 64];
  __shared__ __align__(16) bf16 Bs[NT * 64];

  f32x4 acc[MI][NI];
#pragma unroll
  for (int i = 0; i < MI; ++i)
#pragma unroll
    for (int j = 0; j < NI; ++j)
#pragma unroll
      for (int r = 0; r < 4; ++r) acc[i][j][r] = 0.0f;

  for (int k0 = 0; k0 < 1024; k0 += 64) {
    __syncthreads();
#pragma unroll
    for (int i = 0; i < MT * 8 / NTH; ++i) {
      int lin = i * NTH + tid;
      int row = lin >> 3, p = lin & 7;
      async_copy16(&A[(m0 + row) * 1024 + k0 + ((p ^ (row & 7)) << 3)],
                   &As[(i * NTH + w * 64) * 8]);
    }
#pragma unroll
    for (int i = 0; i < NT * 8 / NTH; ++i) {
      int lin = i * NTH + tid;
      int row = lin >> 3, p = lin & 7;
      async_copy16(&Bt[(n0 + row) * 1024 + k0 + ((p ^ (row & 7)) << 3)],
                   &Bs[(i * NTH + w * 64) * 8]);
    }
    __syncthreads();

#pragma unroll
    for (int kk = 0; kk < 2; ++kk) {
      const int pos = ((kk * 4 + quad) ^ sw) << 3;
      bf16x8 af[MI], bg[NI];
#pragma unroll
      for (int i = 0; i < MI; ++i)
        af[i] = *(const bf16x8*)&As[(mw + i * 16 + m16) * 64 + pos];
#pragma unroll
      for (int j = 0; j < NI; ++j)
        bg[j] = *(const bf16x8*)&Bs[(nw + j * 16 + m16) * 64 + pos];
#pragma unroll
      for (int i = 0; i < MI; ++i)
#pragma unroll
        for (int j = 0; j < NI; ++j) acc[i][j] = mfma16(af[i], bg[j], acc[i][j]);
    }
  }

  const float SC = 0.18033688011112042f;  // (1/8) * log2(e)
#pragma unroll
  for (int i = 0; i < MI; ++i) {
#pragma unroll
    for (int j = 0; j < NI; ++j) {
      int np = n0 + nw + j * 16 + m16;
      if (MODE == 0) {
        int which = np >> 10, n = np & 1023;
        float bias = (which == 0) ? bias0[n] : (which == 1) ? bias1[n] : bias2[n];
        int h = n >> 6, hd = n & 63;
        if (which == 2) {
          // V^T store: pack 4 consecutive s into one 8B store
          bf16x4 pv;
          int m = m0 + mw + i * 16 + quad * 4;
          int b = m >> 11, s = m & 2047;
#pragma unroll
          for (int r = 0; r < 4; ++r) pv[r] = (bf16)(acc[i][j][r] + bias);
          *(bf16x4*)&Vo[((b * 16 + h) * 64 + hd) * 2048 + s] = pv;
        } else {
#pragma unroll
          for (int r = 0; r < 4; ++r) {
            int m = m0 + mw + i * 16 + quad * 4 + r;
            int b = m >> 11, s = m & 2047;
            float v = acc[i][j][r] + bias;
            if (which == 0)
              Qo[((b * 16 + h) * 2048 + s) * 64 + hd] = (bf16)(v * SC);
            else
              Ko[((b * 16 + h) * 2048 + s) * 64 + hd] = (bf16)v;
          }
        }
      } else {
        float bias = bias0[np];
#pragma unroll
        for (int r = 0; r < 4; ++r) {
          int m = m0 + mw + i * 16 + quad * 4 + r;
          Po[m * 1024 + np] = acc[i][j][r] + bias;
        }
      }
    }
  }
}

// ---------------------------------------------------------------- flash attention
// R7 version (best measured: 49.4-49.8 µs) — R8's per-mi P-buffer restructure
// regressed and is reverted.
// grid (B*H, S/128) — bh fast => XCD-local K/V (FETCH 12 MB, R7-verified).
// 256 threads (4 waves, 32 q-rows each via mi=0,1).
// Q: [bh][S][64] bf16 PRE-SCALED by (1/8)log2e; K: [bh][S][64]; Vt: [bh][64][S].
// S^T = K·Q^T; no-max softmax; row-sums via P·1 MFMA.
// K-loop: 2-deep producer pipeline, fine vmcnt + bare s_barrier.
__global__ __launch_bounds__(256, 2) void flash_kernel(const bf16* __restrict__ Q,
                                                       const bf16* __restrict__ K,
                                                       const bf16* __restrict__ Vt,
                                                       bf16* __restrict__ attn) {
  const int S = 2048;
  const int tid = threadIdx.x;
  const int w = tid >> 6, lane = tid & 63, quad = lane >> 4, m16 = lane & 15;
  const int bh = blockIdx.x, b = bh >> 4, h = bh & 15;
  const int qb = blockIdx.y * 128;
  const bf16* Qh = Q + bh * S * 64;
  const bf16* Kh = K + bh * S * 64;
  const bf16* Vh = Vt + bh * 64 * S;

  __shared__ __align__(16) bf16 Ks[2][64 * 64];
  __shared__ __align__(16) bf16 Vs[2][64 * 64];
  __shared__ __align__(16) bf16 Ps[4][16 * 72];  // per-wave P[q][key], pad 64->72

  // Q fragments (B-operand for S^T): wave w owns q rows [qb+w*32, +32)
  bf16x8 qf[2][2];
#pragma unroll
  for (int mi = 0; mi < 2; ++mi)
#pragma unroll
    for (int kk = 0; kk < 2; ++kk)
      qf[mi][kk] = *(const bf16x8*)&Qh[(qb + w * 32 + mi * 16 + m16) * 64 +
                                       kk * 32 + quad * 8];

  bf16x8 ones;
#pragma unroll
  for (int j = 0; j < 8; ++j) ones[j] = (bf16)1.0f;

  f32x4 o[2][4];   // o[mi][dt]: rows q=quad*4+r, cols d=dt*16+m16
  f32x4 lacc[2];   // lacc[mi][r] = running row-sum for q-row quad*4+r
#pragma unroll
  for (int mi = 0; mi < 2; ++mi) {
#pragma unroll
    for (int dt = 0; dt < 4; ++dt)
#pragma unroll
      for (int r = 0; r < 4; ++r) o[mi][dt][r] = 0.0f;
#pragma unroll
    for (int r = 0; r < 4; ++r) lacc[mi][r] = 0.0f;
  }

  // stage K tile [64 keys][64 hd] and V^T tile [64 hd][64 keys], XOR-swizzled.
  auto stage = [&](int kb, int buf) {
#pragma unroll
    for (int i = 0; i < 2; ++i) {
      int lin = i * 256 + tid;
      int row = lin >> 3, g = lin & 7;
      async_copy16(&Kh[(kb + row) * 64 + ((g ^ (row & 7)) << 3)],
                   &Ks[buf][(i * 256 + w * 64) * 8]);
      async_copy16(&Vh[row * 2048 + kb + ((g ^ (row & 7)) << 3)],
                   &Vs[buf][(i * 256 + w * 64) * 8]);
    }
  };

  stage(0, 0);

  for (int t = 0; t < 32; ++t) {
    const int cur = t & 1;
    if (t < 31) {
      stage((t + 1) * 64, cur ^ 1);
      asm volatile("s_waitcnt vmcnt(4)" ::: "memory");  // tile t's 4 oldest done
    } else {
      asm volatile("s_waitcnt vmcnt(0)" ::: "memory");
    }
    asm volatile("s_barrier" ::: "memory");  // tile t fully staged (all waves)

    // hoist K and V fragments once per tile, shared across both mi
    bf16x8 kf[4][2], vf[4][2];
#pragma unroll
    for (int nt = 0; nt < 4; ++nt)
#pragma unroll
      for (int kk = 0; kk < 2; ++kk) {
        int row = nt * 16 + m16;
        int pos = (kk * 4 + quad) ^ (row & 7);
        kf[nt][kk] = *(const bf16x8*)&Ks[cur][row * 64 + pos * 8];
        vf[nt][kk] = *(const bf16x8*)&Vs[cur][row * 64 + pos * 8];
      }
    asm volatile("s_waitcnt lgkmcnt(0)" ::: "memory");  // frags in regs
    asm volatile("s_barrier" ::: "memory");  // buf[cur] free for tile t+2 stage

    bf16* Pw = &Ps[w][0];
#pragma unroll
    for (int mi = 0; mi < 2; ++mi) {
      // S^T = K·Q^T : rows key = nt*16+quad*4+r, cols q = m16 (Q pre-scaled)
      f32x4 sacc[4];
#pragma unroll
      for (int nt = 0; nt < 4; ++nt)
#pragma unroll
        for (int r = 0; r < 4; ++r) sacc[nt][r] = 0.0f;
#pragma unroll
      for (int nt = 0; nt < 4; ++nt)
#pragma unroll
        for (int kk = 0; kk < 2; ++kk)
          sacc[nt] = mfma16(kf[nt][kk], qf[mi][kk], sacc[nt]);

      // P = exp2(S^T); write A-layout P[q=m16][key] — 4 consecutive keys/lane
#pragma unroll
      for (int nt = 0; nt < 4; ++nt) {
        bf16x4 p4;
#pragma unroll
        for (int r = 0; r < 4; ++r)
          p4[r] = (bf16)__builtin_amdgcn_exp2f(sacc[nt][r]);
        *(bf16x4*)&Pw[m16 * 72 + nt * 16 + quad * 4] = p4;
      }
      asm volatile("s_waitcnt lgkmcnt(0)" ::: "memory");

      bf16x8 pf[2];
#pragma unroll
      for (int kk = 0; kk < 2; ++kk)
        pf[kk] = *(const bf16x8*)&Pw[m16 * 72 + kk * 32 + quad * 8];

      // row-sums via MFMA: lacc += P·1  (rows q=quad*4+r, already lane-reduced)
#pragma unroll
      for (int kk = 0; kk < 2; ++kk) lacc[mi] = mfma16(pf[kk], ones, lacc[mi]);

      // O += P·V
#pragma unroll
      for (int dt = 0; dt < 4; ++dt)
#pragma unroll
        for (int kk = 0; kk < 2; ++kk)
          o[mi][dt] = mfma16(pf[kk], vf[dt][kk], o[mi][dt]);
    }
  }

#pragma unroll
  for (int mi = 0; mi < 2; ++mi) {
    f32x4 inv;
#pragma unroll
    for (int r = 0; r < 4; ++r) inv[r] = 1.0f / lacc[mi][r];
#pragma unroll
    for (int dt = 0; dt < 4; ++dt)
#pragma unroll
      for (int r = 0; r < 4; ++r) {
        int s = qb + w * 32 + mi * 16 + quad * 4 + r;
        int col = h * 64 + dt * 16 + m16;
        attn[(b * 2048 + s) * 1024 + col] = (bf16)(o[mi][dt][r] * inv[r]);
      }
  }
}

// ---------------------------------------------------------------- residual + LN
__global__ __launch_bounds__(256) void ln_kernel(const float* __restrict__ x,
                                                 const float* __restrict__ pj,
                                                 const float* __restrict__ gamma,
                                                 const float* __restrict__ beta,
                                                 float* __restrict__ out) {
  int row = blockIdx.x, t = threadIdx.x;
  int base = row * 1024 + t * 4;
  float4 xv = *(const float4*)&x[base];
  float4 pv = *(const float4*)&pj[base];
  float y0 = xv.x + pv.x, y1 = xv.y + pv.y, y2 = xv.z + pv.z, y3 = xv.w + pv.w;
  float s = y0 + y1 + y2 + y3;
  float ss = y0 * y0 + y1 * y1 + y2 * y2 + y3 * y3;
  for (int m = 1; m < 64; m <<= 1) {
    s += __shfl_xor(s, m);
    ss += __shfl_xor(ss, m);
  }
  __shared__ float sred[8];
  int w = t >> 6;
  if ((t & 63) == 0) { sred[w * 2] = s; sred[w * 2 + 1] = ss; }
  __syncthreads();
  s = sred[0] + sred[2] + sred[4] + sred[6];
  ss = sred[1] + sred[3] + sred[5] + sred[7];
  float mean = s * (1.0f / 1024.0f);
  float var = ss * (1.0f / 1024.0f) - mean * mean;
  float rstd = rsqrtf(var + 1e-5f);
  float4 gv = *(const float4*)&gamma[t * 4];
  float4 bv = *(const float4*)&beta[t * 4];
  float4 ov;
  ov.x = (y0 - mean) * rstd * gv.x + bv.x;
  ov.y = (y1 - mean) * rstd * gv.y + bv.y;
  ov.z = (y2 - mean) * rstd * gv.z + bv.z;
  ov.w = (y3 - mean) * rstd * gv.w + bv.w;
  *(float4*)&out[base] = ov;
}

// ---------------------------------------------------------------- launch

extern "C" void kernel_launch(void* const* d_in, const int* in_sizes, int n_in,
                              void* d_out, int out_size, void* d_ws, size_t ws_size,
                              hipStream_t stream) {
  const float* x = (const float*)d_in[0];
  const float* Wq = (const float*)d_in[1];
  const float* bq = (const float*)d_in[2];
  const float* Wk = (const float*)d_in[3];
  const float* bk = (const float*)d_in[4];
  const float* Wv = (const float*)d_in[5];
  const float* bv = (const float*)d_in[6];
  const float* Wp = (const float*)d_in[7];
  const float* bp = (const float*)d_in[8];
  const float* gamma = (const float*)d_in[9];
  const float* beta = (const float*)d_in[10];
  float* out = (float*)d_out;

  char* ws = (char*)d_ws;
  // layout (bytes): [0,8M) xb -> reused as attn ; [8M,16M) Wt ; [16M,24M) Q ;
  // [24M,32M) K ; [32M,40M) Vt ; proj fp32 reuses [16M,32M). Total 40 MB.
  bf16* xb = (bf16*)(ws);
  bf16* Wtb = (bf16*)(ws + (8u << 20));
  bf16* Qb = (bf16*)(ws + (16u << 20));
  bf16* Kb = (bf16*)(ws + (24u << 20));
  bf16* Vtb = (bf16*)(ws + (32u << 20));
  float* proj = (float*)(ws + (16u << 20));
  bf16* attn = xb;

  prep<<<dim3(32, 32, 5), 256, 0, stream>>>(x, Wq, Wk, Wv, Wp, xb, Wtb);
  gemm_bt<0, 128, 128, 2><<<dim3(32, 24), 128, 0, stream>>>(
      xb, Wtb, bq, bk, bv, Qb, Kb, Vtb, nullptr);
  flash_kernel<<<dim3(32, 16), 256, 0, stream>>>(Qb, Kb, Vtb, attn);
  gemm_bt<1, 64, 128, 4><<<dim3(64, 8), 256, 0, stream>>>(
      attn, Wtb + 3072 * 1024, bp, nullptr, nullptr, nullptr, nullptr, nullptr,
      proj);
  ln_kernel<<<4096, 256, 0, stream>>>(x, proj, gamma, beta, out);
}

// Round 11
// 186.667 us; speedup vs baseline: 1.0378x; 1.0378x over previous
//
#include <hip/hip_runtime.h>

#define DI __device__ __forceinline__

typedef __bf16 bf16;
typedef __bf16 bf16x8 __attribute__((ext_vector_type(8)));
typedef __bf16 bf16x4 __attribute__((ext_vector_type(4)));
typedef float  f32x4  __attribute__((ext_vector_type(4)));

DI void async_copy16(const void* g, void* s) {
  __builtin_amdgcn_global_load_lds(
      (__attribute__((address_space(1))) unsigned int*)(void*)g,
      (__attribute__((address_space(3))) unsigned int*)s,
      16, 0, 0);
}

DI f32x4 mfma16(bf16x8 a, bf16x8 b, f32x4 c) {
  return __builtin_amdgcn_mfma_f32_16x16x32_bf16(a, b, c, 0, 0, 0);
}

// ---------------------------------------------------------------- prep kernel
// z==4: x fp32 -> bf16 (1024 virtual blocks x 4096 elems).
// z<4 : Wt[z*1024 + n][k] = W_z[k][n] (bf16) — B^T layout for gemm_bt.
__global__ __launch_bounds__(256) void prep(const float* __restrict__ x,
                                            const float* __restrict__ Wq,
                                            const float* __restrict__ Wk,
                                            const float* __restrict__ Wv,
                                            const float* __restrict__ Wp,
                                            bf16* __restrict__ xb,
                                            bf16* __restrict__ Wt) {
  if (blockIdx.z == 4) {
    int blk = blockIdx.y * 32 + blockIdx.x;  // 0..1023
    int base = blk * 4096 + threadIdx.x * 4;
#pragma unroll
    for (int j = 0; j < 4; ++j) {
      float4 v = *(const float4*)&x[base + j * 1024];
      bf16x4 o;
      o[0] = (bf16)v.x; o[1] = (bf16)v.y; o[2] = (bf16)v.z; o[3] = (bf16)v.w;
      *(bf16x4*)&xb[base + j * 1024] = o;
    }
    return;
  }
  __shared__ float tile[32][33];
  const float* W = (blockIdx.z == 0) ? Wq : (blockIdx.z == 1) ? Wk
                 : (blockIdx.z == 2) ? Wv : Wp;
  int n0 = blockIdx.x * 32, k0 = blockIdx.y * 32;
  int tx = threadIdx.x & 31, ty = threadIdx.x >> 5;  // virtual (32,8)
#pragma unroll
  for (int i = 0; i < 4; ++i)
    tile[ty + i * 8][tx] = W[(k0 + ty + i * 8) * 1024 + n0 + tx];
  __syncthreads();
#pragma unroll
  for (int i = 0; i < 4; ++i)
    Wt[((int)blockIdx.z * 1024 + n0 + ty + i * 8) * 1024 + k0 + tx] =
        (bf16)tile[tx][ty + i * 8];
}

// ---------------------------------------------------------------- GEMM (B^T)
// 4-wave 2x2 wave-grid version (R8-bench config — the R9 2-wave retile
// regressed ~10 µs and is reverted).
// C[m][n] = sum_k A[m][k] * Bt[n][k]  + bias.   BK=64 (rows = 128 B = 32 banks)
// with XOR-8 chunk swizzle on LDS tiles (2-way bank aliasing only, free).
// MODE 0 (128x128): N=3072 QKV. Writes Q (pre-scaled (1/8)log2e), K as
//   [B,H,S,64] bf16; V as [B,H,64,S] bf16.
// MODE 1 (64x128): N=1024 proj -> bf16 [4096][1024] + bias (bf16 halves the
//   proj->LN traffic; error ~0.004 vs 0.1 threshold).
template <int MODE, int MT, int NT>
__global__ __launch_bounds__(256, 3) void gemm_bt(
    const bf16* __restrict__ A, const bf16* __restrict__ Bt,
    const float* __restrict__ bias0, const float* __restrict__ bias1,
    const float* __restrict__ bias2, bf16* __restrict__ Qo,
    bf16* __restrict__ Ko, bf16* __restrict__ Vo, bf16* __restrict__ Po) {
  constexpr int MW = MT / 2, NW = NT / 2;  // per-wave tile (2x2 wave grid)
  constexpr int MI = MW / 16, NI = NW / 16;
  const int tid = threadIdx.x;
  const int w = tid >> 6, lane = tid & 63, quad = lane >> 4, m16 = lane & 15;
  const int m0 = blockIdx.x * MT, n0 = blockIdx.y * NT;
  const int mw = (w >> 1) * MW, nw = (w & 1) * NW;
  const int sw = m16 & 7;

  __shared__ __align__(16) bf16 As[MT * 64];
  __shared__ __align__(16) bf16 Bs[NT * 64];

  f32x4 acc[MI][NI];
#pragma unroll
  for (int i = 0; i < MI; ++i)
#pragma unroll
    for (int j = 0; j < NI; ++j)
#pragma unroll
      for (int r = 0; r < 4; ++r) acc[i][j][r] = 0.0f;

  for (int k0 = 0; k0 < 1024; k0 += 64) {
    __syncthreads();
#pragma unroll
    for (int i = 0; i < MT / 32; ++i) {
      int lin = i * 256 + tid;
      int row = lin >> 3, p = lin & 7;
      async_copy16(&A[(m0 + row) * 1024 + k0 + ((p ^ (row & 7)) << 3)],
                   &As[(i * 256 + w * 64) * 8]);
    }
#pragma unroll
    for (int i = 0; i < NT / 32; ++i) {
      int lin = i * 256 + tid;
      int row = lin >> 3, p = lin & 7;
      async_copy16(&Bt[(n0 + row) * 1024 + k0 + ((p ^ (row & 7)) << 3)],
                   &Bs[(i * 256 + w * 64) * 8]);
    }
    __syncthreads();

#pragma unroll
    for (int kk = 0; kk < 2; ++kk) {
      const int pos = ((kk * 4 + quad) ^ sw) << 3;
      bf16x8 af[MI], bg[NI];
#pragma unroll
      for (int i = 0; i < MI; ++i)
        af[i] = *(const bf16x8*)&As[(mw + i * 16 + m16) * 64 + pos];
#pragma unroll
      for (int j = 0; j < NI; ++j)
        bg[j] = *(const bf16x8*)&Bs[(nw + j * 16 + m16) * 64 + pos];
#pragma unroll
      for (int i = 0; i < MI; ++i)
#pragma unroll
        for (int j = 0; j < NI; ++j) acc[i][j] = mfma16(af[i], bg[j], acc[i][j]);
    }
  }

  const float SC = 0.18033688011112042f;  // (1/8) * log2(e)
#pragma unroll
  for (int i = 0; i < MI; ++i) {
#pragma unroll
    for (int j = 0; j < NI; ++j) {
      int np = n0 + nw + j * 16 + m16;
      if (MODE == 0) {
        int which = np >> 10, n = np & 1023;
        float bias = (which == 0) ? bias0[n] : (which == 1) ? bias1[n] : bias2[n];
        int h = n >> 6, hd = n & 63;
        if (which == 2) {
          // V^T store: pack 4 consecutive s into one 8B store
          bf16x4 pv;
          int m = m0 + mw + i * 16 + quad * 4;
          int b = m >> 11, s = m & 2047;
#pragma unroll
          for (int r = 0; r < 4; ++r) pv[r] = (bf16)(acc[i][j][r] + bias);
          *(bf16x4*)&Vo[((b * 16 + h) * 64 + hd) * 2048 + s] = pv;
        } else {
#pragma unroll
          for (int r = 0; r < 4; ++r) {
            int m = m0 + mw + i * 16 + quad * 4 + r;
            int b = m >> 11, s = m & 2047;
            float v = acc[i][j][r] + bias;
            if (which == 0)
              Qo[((b * 16 + h) * 2048 + s) * 64 + hd] = (bf16)(v * SC);
            else
              Ko[((b * 16 + h) * 2048 + s) * 64 + hd] = (bf16)v;
          }
        }
      } else {
        float bias = bias0[np];
#pragma unroll
        for (int r = 0; r < 4; ++r) {
          int m = m0 + mw + i * 16 + quad * 4 + r;
          Po[m * 1024 + np] = (bf16)(acc[i][j][r] + bias);
        }
      }
    }
  }
}

// ---------------------------------------------------------------- flash attention
// R7-good body (best measured: 49.4-50.1 µs; R8 per-mi and R6 key-split
// restructures both regressed — frozen).
// grid (B*H, S/128) — bh fast => XCD-local K/V (FETCH 12 MB, R7-verified).
// 256 threads (4 waves, 32 q-rows each via mi=0,1).
// Q: [bh][S][64] bf16 PRE-SCALED by (1/8)log2e; K: [bh][S][64]; Vt: [bh][64][S].
// S^T = K·Q^T; no-max softmax; row-sums via P·1 MFMA.
// K-loop: 2-deep producer pipeline, fine vmcnt + bare s_barrier.
__global__ __launch_bounds__(256, 2) void flash_kernel(const bf16* __restrict__ Q,
                                                       const bf16* __restrict__ K,
                                                       const bf16* __restrict__ Vt,
                                                       bf16* __restrict__ attn) {
  const int S = 2048;
  const int tid = threadIdx.x;
  const int w = tid >> 6, lane = tid & 63, quad = lane >> 4, m16 = lane & 15;
  const int bh = blockIdx.x, b = bh >> 4, h = bh & 15;
  const int qb = blockIdx.y * 128;
  const bf16* Qh = Q + bh * S * 64;
  const bf16* Kh = K + bh * S * 64;
  const bf16* Vh = Vt + bh * 64 * S;

  __shared__ __align__(16) bf16 Ks[2][64 * 64];
  __shared__ __align__(16) bf16 Vs[2][64 * 64];
  __shared__ __align__(16) bf16 Ps[4][16 * 72];  // per-wave P[q][key], pad 64->72

  // Q fragments (B-operand for S^T): wave w owns q rows [qb+w*32, +32)
  bf16x8 qf[2][2];
#pragma unroll
  for (int mi = 0; mi < 2; ++mi)
#pragma unroll
    for (int kk = 0; kk < 2; ++kk)
      qf[mi][kk] = *(const bf16x8*)&Qh[(qb + w * 32 + mi * 16 + m16) * 64 +
                                       kk * 32 + quad * 8];

  bf16x8 ones;
#pragma unroll
  for (int j = 0; j < 8; ++j) ones[j] = (bf16)1.0f;

  f32x4 o[2][4];   // o[mi][dt]: rows q=quad*4+r, cols d=dt*16+m16
  f32x4 lacc[2];   // lacc[mi][r] = running row-sum for q-row quad*4+r
#pragma unroll
  for (int mi = 0; mi < 2; ++mi) {
#pragma unroll
    for (int dt = 0; dt < 4; ++dt)
#pragma unroll
      for (int r = 0; r < 4; ++r) o[mi][dt][r] = 0.0f;
#pragma unroll
    for (int r = 0; r < 4; ++r) lacc[mi][r] = 0.0f;
  }

  // stage K tile [64 keys][64 hd] and V^T tile [64 hd][64 keys], XOR-swizzled.
  auto stage = [&](int kb, int buf) {
#pragma unroll
    for (int i = 0; i < 2; ++i) {
      int lin = i * 256 + tid;
      int row = lin >> 3, g = lin & 7;
      async_copy16(&Kh[(kb + row) * 64 + ((g ^ (row & 7)) << 3)],
                   &Ks[buf][(i * 256 + w * 64) * 8]);
      async_copy16(&Vh[row * 2048 + kb + ((g ^ (row & 7)) << 3)],
                   &Vs[buf][(i * 256 + w * 64) * 8]);
    }
  };

  stage(0, 0);

  for (int t = 0; t < 32; ++t) {
    const int cur = t & 1;
    if (t < 31) {
      stage((t + 1) * 64, cur ^ 1);
      asm volatile("s_waitcnt vmcnt(4)" ::: "memory");  // tile t's 4 oldest done
    } else {
      asm volatile("s_waitcnt vmcnt(0)" ::: "memory");
    }
    asm volatile("s_barrier" ::: "memory");  // tile t fully staged (all waves)

    // hoist K and V fragments once per tile, shared across both mi
    bf16x8 kf[4][2], vf[4][2];
#pragma unroll
    for (int nt = 0; nt < 4; ++nt)
#pragma unroll
      for (int kk = 0; kk < 2; ++kk) {
        int row = nt * 16 + m16;
        int pos = (kk * 4 + quad) ^ (row & 7);
        kf[nt][kk] = *(const bf16x8*)&Ks[cur][row * 64 + pos * 8];
        vf[nt][kk] = *(const bf16x8*)&Vs[cur][row * 64 + pos * 8];
      }
    asm volatile("s_waitcnt lgkmcnt(0)" ::: "memory");  // frags in regs
    asm volatile("s_barrier" ::: "memory");  // buf[cur] free for tile t+2 stage

    bf16* Pw = &Ps[w][0];
#pragma unroll
    for (int mi = 0; mi < 2; ++mi) {
      // S^T = K·Q^T : rows key = nt*16+quad*4+r, cols q = m16 (Q pre-scaled)
      f32x4 sacc[4];
#pragma unroll
      for (int nt = 0; nt < 4; ++nt)
#pragma unroll
        for (int r = 0; r < 4; ++r) sacc[nt][r] = 0.0f;
#pragma unroll
      for (int nt = 0; nt < 4; ++nt)
#pragma unroll
        for (int kk = 0; kk < 2; ++kk)
          sacc[nt] = mfma16(kf[nt][kk], qf[mi][kk], sacc[nt]);

      // P = exp2(S^T); write A-layout P[q=m16][key] — 4 consecutive keys/lane
#pragma unroll
      for (int nt = 0; nt < 4; ++nt) {
        bf16x4 p4;
#pragma unroll
        for (int r = 0; r < 4; ++r)
          p4[r] = (bf16)__builtin_amdgcn_exp2f(sacc[nt][r]);
        *(bf16x4*)&Pw[m16 * 72 + nt * 16 + quad * 4] = p4;
      }
      asm volatile("s_waitcnt lgkmcnt(0)" ::: "memory");

      bf16x8 pf[2];
#pragma unroll
      for (int kk = 0; kk < 2; ++kk)
        pf[kk] = *(const bf16x8*)&Pw[m16 * 72 + kk * 32 + quad * 8];

      // row-sums via MFMA: lacc += P·1  (rows q=quad*4+r, already lane-reduced)
#pragma unroll
      for (int kk = 0; kk < 2; ++kk) lacc[mi] = mfma16(pf[kk], ones, lacc[mi]);

      // O += P·V
#pragma unroll
      for (int dt = 0; dt < 4; ++dt)
#pragma unroll
        for (int kk = 0; kk < 2; ++kk)
          o[mi][dt] = mfma16(pf[kk], vf[dt][kk], o[mi][dt]);
    }
  }

#pragma unroll
  for (int mi = 0; mi < 2; ++mi) {
    f32x4 inv;
#pragma unroll
    for (int r = 0; r < 4; ++r) inv[r] = 1.0f / lacc[mi][r];
#pragma unroll
    for (int dt = 0; dt < 4; ++dt)
#pragma unroll
      for (int r = 0; r < 4; ++r) {
        int s = qb + w * 32 + mi * 16 + quad * 4 + r;
        int col = h * 64 + dt * 16 + m16;
        attn[(b * 2048 + s) * 1024 + col] = (bf16)(o[mi][dt][r] * inv[r]);
      }
  }
}

// ---------------------------------------------------------------- residual + LN
// pj is now bf16 (proj GEMM writes bf16) — halves proj->LN memory traffic.
__global__ __launch_bounds__(256) void ln_kernel(const float* __restrict__ x,
                                                 const bf16* __restrict__ pj,
                                                 const float* __restrict__ gamma,
                                                 const float* __restrict__ beta,
                                                 float* __restrict__ out) {
  int row = blockIdx.x, t = threadIdx.x;
  int base = row * 1024 + t * 4;
  float4 xv = *(const float4*)&x[base];
  bf16x4 pv4 = *(const bf16x4*)&pj[base];
  float y0 = xv.x + (float)pv4[0], y1 = xv.y + (float)pv4[1];
  float y2 = xv.z + (float)pv4[2], y3 = xv.w + (float)pv4[3];
  float s = y0 + y1 + y2 + y3;
  float ss = y0 * y0 + y1 * y1 + y2 * y2 + y3 * y3;
  for (int m = 1; m < 64; m <<= 1) {
    s += __shfl_xor(s, m);
    ss += __shfl_xor(ss, m);
  }
  __shared__ float sred[8];
  int w = t >> 6;
  if ((t & 63) == 0) { sred[w * 2] = s; sred[w * 2 + 1] = ss; }
  __syncthreads();
  s = sred[0] + sred[2] + sred[4] + sred[6];
  ss = sred[1] + sred[3] + sred[5] + sred[7];
  float mean = s * (1.0f / 1024.0f);
  float var = ss * (1.0f / 1024.0f) - mean * mean;
  float rstd = rsqrtf(var + 1e-5f);
  float4 gv = *(const float4*)&gamma[t * 4];
  float4 bv = *(const float4*)&beta[t * 4];
  float4 ov;
  ov.x = (y0 - mean) * rstd * gv.x + bv.x;
  ov.y = (y1 - mean) * rstd * gv.y + bv.y;
  ov.z = (y2 - mean) * rstd * gv.z + bv.z;
  ov.w = (y3 - mean) * rstd * gv.w + bv.w;
  *(float4*)&out[base] = ov;
}

// ---------------------------------------------------------------- launch

extern "C" void kernel_launch(void* const* d_in, const int* in_sizes, int n_in,
                              void* d_out, int out_size, void* d_ws, size_t ws_size,
                              hipStream_t stream) {
  const float* x = (const float*)d_in[0];
  const float* Wq = (const float*)d_in[1];
  const float* bq = (const float*)d_in[2];
  const float* Wk = (const float*)d_in[3];
  const float* bk = (const float*)d_in[4];
  const float* Wv = (const float*)d_in[5];
  const float* bv = (const float*)d_in[6];
  const float* Wp = (const float*)d_in[7];
  const float* bp = (const float*)d_in[8];
  const float* gamma = (const float*)d_in[9];
  const float* beta = (const float*)d_in[10];
  float* out = (float*)d_out;

  char* ws = (char*)d_ws;
  // layout (bytes): [0,8M) xb -> reused as attn ; [8M,16M) Wt ; [16M,24M) Q ;
  // [24M,32M) K ; [32M,40M) Vt ; proj bf16 reuses [16M,24M). Total 40 MB.
  bf16* xb = (bf16*)(ws);
  bf16* Wtb = (bf16*)(ws + (8u << 20));
  bf16* Qb = (bf16*)(ws + (16u << 20));
  bf16* Kb = (bf16*)(ws + (24u << 20));
  bf16* Vtb = (bf16*)(ws + (32u << 20));
  bf16* proj = (bf16*)(ws + (16u << 20));
  bf16* attn = xb;

  prep<<<dim3(32, 32, 5), 256, 0, stream>>>(x, Wq, Wk, Wv, Wp, xb, Wtb);
  gemm_bt<0, 128, 128><<<dim3(32, 24), 256, 0, stream>>>(
      xb, Wtb, bq, bk, bv, Qb, Kb, Vtb, nullptr);
  flash_kernel<<<dim3(32, 16), 256, 0, stream>>>(Qb, Kb, Vtb, attn);
  gemm_bt<1, 64, 128><<<dim3(64, 8), 256, 0, stream>>>(
      attn, Wtb + 3072 * 1024, bp, nullptr, nullptr, nullptr, nullptr, nullptr,
      proj);
  ln_kernel<<<4096, 256, 0, stream>>>(x, proj, gamma, beta, out);
}